// Round 6
// baseline (985.571 us; speedup 1.0000x reference)
//
#include <hip/hip_runtime.h>
#include <math.h>

#define BATCH    65536
#define HID      128
#define SELF_DIM 18
#define NBR_DIM  6
#define OBS_W    66
#define RB       64      // rows per block
#define NTHREADS 512     // 8 waves: 2 row-halves x 4 col-quarters
#define X0S      32      // pow2 LDS stride for the 24-wide input (zero-padded)

using bf16x8 = __attribute__((ext_vector_type(8))) short;
using f32x4  = __attribute__((ext_vector_type(4))) float;

// ---- ws layout (element offsets into a short*) ----
#define E1H 0            // eW1^T hi  [128][32]
#define E1L 4096
#define E2H 8192         // eW2^T hi  [128][128]
#define E2L 24576
#define V1H 40960
#define V1L 57344
#define V2H 73728
#define V2L 90112
#define A1H 106496       // aW1^T hi  [128][256]
#define A1L 139264
#define A2H 172032
#define A2L 188416
#define MEANH 204800     // mean hi   [BATCH][128]
#define MEANL (MEANH + BATCH*HID)
#define WS_ELEMS_FULL (MEANL + BATCH*HID)

__device__ __forceinline__ float4 ld4(const float* p) { return *reinterpret_cast<const float4*>(p); }

__device__ __forceinline__ unsigned cvtpk(float a, float b) {
    unsigned r;
    asm("v_cvt_pk_bf16_f32 %0, %1, %2" : "=v"(r) : "v"(a), "v"(b));
    return r;
}

// tanh = 1 - 2/(2^(2*log2e*x)+1); inf-safe at both ends
__device__ __forceinline__ float tanh_f(float x) {
    float t = __builtin_amdgcn_exp2f(x * 2.8853900817779268f);
    float r = __builtin_amdgcn_rcpf(t + 1.f);
    return 1.f - 2.f * r;
}

__device__ __forceinline__ f32x4 mfma16(bf16x8 a, bf16x8 b, f32x4 c) {
    return __builtin_amdgcn_mfma_f32_16x16x32_bf16(a, b, c, 0, 0, 0);
}
__device__ __forceinline__ void zacc(f32x4 acc[2][2]) {
    #pragma unroll
    for (int rt = 0; rt < 2; ++rt)
        #pragma unroll
        for (int ct = 0; ct < 2; ++ct) acc[rt][ct] = f32x4{0.f, 0.f, 0.f, 0.f};
}

// ---- W fragments (prefetched into registers, consumed after a barrier) ----
struct WF1 { bf16x8 h0, h1, l0, l1; };
struct WF4 { bf16x8 h0[4], h1[4], l0[4], l1[4]; };

template<int KEL>
__device__ __forceinline__ WF1 loadW1(const short* __restrict__ Wh, const short* __restrict__ Wl) {
    WF1 f;
    f.h0 = *(const bf16x8*)(Wh);            f.h1 = *(const bf16x8*)(Wh + 16 * KEL);
    f.l0 = *(const bf16x8*)(Wl);            f.l1 = *(const bf16x8*)(Wl + 16 * KEL);
    return f;
}
template<int KEL>
__device__ __forceinline__ WF4 loadW4(const short* __restrict__ Wh, const short* __restrict__ Wl) {
    WF4 f;
    #pragma unroll
    for (int ks = 0; ks < 4; ++ks) {
        f.h0[ks] = *(const bf16x8*)(Wh + ks * 32);
        f.h1[ks] = *(const bf16x8*)(Wh + 16 * KEL + ks * 32);
        f.l0[ks] = *(const bf16x8*)(Wl + ks * 32);
        f.l1[ks] = *(const bf16x8*)(Wl + 16 * KEL + ks * 32);
    }
    return f;
}

// single-ks layer (K=32): 12 MFMAs
__device__ __forceinline__ void mmT1(f32x4 acc[2][2], const WF1& f,
        const short* xh, const short* xl)
{
    bf16x8 ah0 = *(const bf16x8*)(xh);
    bf16x8 ah1 = *(const bf16x8*)(xh + 512);
    bf16x8 al0 = *(const bf16x8*)(xl);
    bf16x8 al1 = *(const bf16x8*)(xl + 512);
    __builtin_amdgcn_s_setprio(1);
    acc[0][0] = mfma16(f.h0, ah0, acc[0][0]); acc[0][1] = mfma16(f.h1, ah0, acc[0][1]);
    acc[1][0] = mfma16(f.h0, ah1, acc[1][0]); acc[1][1] = mfma16(f.h1, ah1, acc[1][1]);
    acc[0][0] = mfma16(f.h0, al0, acc[0][0]); acc[0][1] = mfma16(f.h1, al0, acc[0][1]);
    acc[1][0] = mfma16(f.h0, al1, acc[1][0]); acc[1][1] = mfma16(f.h1, al1, acc[1][1]);
    acc[0][0] = mfma16(f.l0, ah0, acc[0][0]); acc[0][1] = mfma16(f.l1, ah0, acc[0][1]);
    acc[1][0] = mfma16(f.l0, ah1, acc[1][0]); acc[1][1] = mfma16(f.l1, ah1, acc[1][1]);
    __builtin_amdgcn_s_setprio(0);
}

// 4-ks layer (K=128): 48 MFMAs; B-frags from swizzled LDS (even/odd-ks base ptrs)
__device__ __forceinline__ void mmT4(f32x4 acc[2][2], const WF4& f,
        const short* xhE, const short* xhO, const short* xlE, const short* xlO)
{
    #pragma unroll
    for (int ks = 0; ks < 4; ++ks) {
        const short* xh = (ks & 1) ? xhO : xhE;
        const short* xl = (ks & 1) ? xlO : xlE;
        bf16x8 ah0 = *(const bf16x8*)(xh + ks * 32);
        bf16x8 ah1 = *(const bf16x8*)(xh + ks * 32 + 2048);
        bf16x8 al0 = *(const bf16x8*)(xl + ks * 32);
        bf16x8 al1 = *(const bf16x8*)(xl + ks * 32 + 2048);
        __builtin_amdgcn_s_setprio(1);
        acc[0][0] = mfma16(f.h0[ks], ah0, acc[0][0]); acc[0][1] = mfma16(f.h1[ks], ah0, acc[0][1]);
        acc[1][0] = mfma16(f.h0[ks], ah1, acc[1][0]); acc[1][1] = mfma16(f.h1[ks], ah1, acc[1][1]);
        acc[0][0] = mfma16(f.h0[ks], al0, acc[0][0]); acc[0][1] = mfma16(f.h1[ks], al0, acc[0][1]);
        acc[1][0] = mfma16(f.h0[ks], al1, acc[1][0]); acc[1][1] = mfma16(f.h1[ks], al1, acc[1][1]);
        acc[0][0] = mfma16(f.l0[ks], ah0, acc[0][0]); acc[0][1] = mfma16(f.l1[ks], ah0, acc[0][1]);
        acc[1][0] = mfma16(f.l0[ks], ah1, acc[1][0]); acc[1][1] = mfma16(f.l1[ks], ah1, acc[1][1]);
        __builtin_amdgcn_s_setprio(0);
    }
}

// tanh(acc + bias) -> hi/lo split -> b64 stores (swizzled layout)
__device__ __forceinline__ void epi_tanh_store(const f32x4 acc[2][2], const float* __restrict__ bias,
        short* Xh, short* Xl, int j00, int st0, int st1)
{
    #pragma unroll
    for (int ct = 0; ct < 2; ++ct) {
        float4 bb = ld4(&bias[j00 + ct * 16]);
        const int st = ct ? st1 : st0;
        #pragma unroll
        for (int rt = 0; rt < 2; ++rt) {
            float v0 = tanh_f(acc[rt][ct][0] + bb.x);
            float v1 = tanh_f(acc[rt][ct][1] + bb.y);
            float v2 = tanh_f(acc[rt][ct][2] + bb.z);
            float v3 = tanh_f(acc[rt][ct][3] + bb.w);
            unsigned h01 = cvtpk(v0, v1), h23 = cvtpk(v2, v3);
            float f0 = __uint_as_float(h01 << 16), f1 = __uint_as_float(h01 & 0xffff0000u);
            float f2 = __uint_as_float(h23 << 16), f3 = __uint_as_float(h23 & 0xffff0000u);
            unsigned l01 = cvtpk(v0 - f0, v1 - f1), l23 = cvtpk(v2 - f2, v3 - f3);
            *reinterpret_cast<uint2*>(Xh + st + rt * 2048) = make_uint2(h01, h23);
            *reinterpret_cast<uint2*>(Xl + st + rt * 2048) = make_uint2(l01, l23);
        }
    }
}

// build X0 rows: [self_obs[r % B] | obs[r/8] nbr slice | zeros], split hi/lo
__device__ __forceinline__ void build_x0(short* X0h, short* X0l,
        const float* __restrict__ self_obs, const float* __restrict__ obs,
        int r0, int tid)
{
    for (int idx = tid; idx < RB * X0S; idx += NTHREADS) {
        int s = idx >> 5, c = idx & 31;
        int r = r0 + s;
        float v = 0.f;
        if (c < SELF_DIM) v = self_obs[(size_t)(r & (BATCH - 1)) * SELF_DIM + c];
        else if (c < 24)  v = obs[(size_t)(r >> 3) * OBS_W + SELF_DIM + (r & 7) * NBR_DIM + (c - SELF_DIM)];
        unsigned u = __float_as_uint(v);
        unsigned h = (u + 0x7fffu + ((u >> 16) & 1u)) >> 16;
        float lf = v - __uint_as_float(h << 16);
        X0h[idx] = (short)h;
        X0l[idx] = (short)(__float_as_uint(lf) >> 16);
    }
}

// ================= prep: W -> W^T bf16 hi/lo in ws =================
__global__ void prep_w(const float* __restrict__ eW1, const float* __restrict__ eW2,
                       const float* __restrict__ vW1, const float* __restrict__ vW2,
                       const float* __restrict__ aW1, const float* __restrict__ aW2,
                       short* __restrict__ ws)
{
    int t = blockIdx.x * blockDim.x + threadIdx.x;
    float v; int dh, dl;
    if (t < 4096)        { int u = t;          int c = u >> 5, k = u & 31;
                           v = (k < 24) ? eW1[k * HID + c] : 0.f; dh = E1H + u; dl = E1L + u; }
    else if (t < 20480)  { int u = t - 4096;   int c = u >> 7, k = u & 127;
                           v = eW2[k * HID + c]; dh = E2H + u; dl = E2L + u; }
    else if (t < 36864)  { int u = t - 20480;  int c = u >> 7, k = u & 127;
                           v = vW1[k * HID + c]; dh = V1H + u; dl = V1L + u; }
    else if (t < 53248)  { int u = t - 36864;  int c = u >> 7, k = u & 127;
                           v = vW2[k * HID + c]; dh = V2H + u; dl = V2L + u; }
    else if (t < 86016)  { int u = t - 53248;  int c = u >> 8, k = u & 255;
                           v = aW1[k * HID + c]; dh = A1H + u; dl = A1L + u; }
    else if (t < 102400) { int u = t - 86016;  int c = u >> 7, k = u & 127;
                           v = aW2[k * HID + c]; dh = A2H + u; dl = A2L + u; }
    else return;
    unsigned uu = __float_as_uint(v);
    unsigned h = (uu + 0x7fffu + ((uu >> 16) & 1u)) >> 16;
    float lf = v - __uint_as_float(h << 16);
    ws[dh] = (short)h;
    ws[dl] = (short)(__float_as_uint(lf) >> 16);
}

// XCD-aware bijection: the 8 logical blocks {g, g+1024, ...} (which share the same
// self/mean window g) land on hw ids congruent mod 8 (same XCD), in adjacent slots.
__device__ __forceinline__ int remap_bid(int hw) {
    return (((hw >> 3) & 7) << 10) | ((hw >> 6) << 3) | (hw & 7);
}

// ================= kernel A: emb -> group means (bf16 hi/lo to ws) =================
__global__ __launch_bounds__(NTHREADS, 4)
void qk_mean(const float* __restrict__ self_obs, const float* __restrict__ obs,
             const float* __restrict__ eb1, const float* __restrict__ eb2,
             short* __restrict__ ws, int use_ml)
{
    __shared__ __align__(16) short X0h[RB * X0S], X0l[RB * X0S];
    __shared__ __align__(16) short XPh[RB * HID], XPl[RB * HID];

    const int tid = threadIdx.x, lane = tid & 63, w = tid >> 6;
    const int wr = w >> 2, wc = w & 3;
    const int lm = lane & 15, q = lane >> 4, q8 = q << 3;
    const int swz = (lm & 7) << 3;
    const int swz_lo = swz & 0x18, swz_hi = swz & 0x20;
    const int rowb = wr * 32 + lm;
    const int xboff = rowb * HID + (q8 ^ swz_lo);
    const int xbE = xboff + swz_hi, xbO = xboff - swz_hi;
    const int j00 = wc * 32 + (q << 2);
    const int st0 = rowb * HID + ((wc * 32 + (q << 2)) ^ swz);
    const int st1 = rowb * HID + ((wc * 32 + 16 + (q << 2)) ^ swz);
    const int x0off = rowb * X0S + q8;
    const int c0 = wc * 32 + lm;
    const int off32 = c0 * 32 + q8, off128 = c0 * 128 + q8;
    const int bidx = remap_bid(blockIdx.x);
    const int r0 = bidx * RB;

    WF1 f1 = loadW1<32>(ws + E1H + off32, ws + E1L + off32);
    build_x0(X0h, X0l, self_obs, obs, r0, tid);
    __syncthreads();

    f32x4 acc[2][2];
    zacc(acc);
    mmT1(acc, f1, X0h + x0off, X0l + x0off);
    WF4 f2 = loadW4<128>(ws + E2H + off128, ws + E2L + off128);
    epi_tanh_store(acc, eb1, XPh, XPl, j00, st0, st1);
    __syncthreads();

    zacc(acc);
    mmT4(acc, f2, XPh + xbE, XPh + xbO, XPl + xbE, XPl + xbO);
    // mean reduce (8 consecutive rows) -> ws
    {
        short* mh  = ws + MEANH;
        short* mlp = ws + MEANL;
        #pragma unroll
        for (int ct = 0; ct < 2; ++ct) {
            float4 bb = ld4(&eb2[j00 + ct * 16]);
            #pragma unroll
            for (int rt = 0; rt < 2; ++rt) {
                float v0 = tanh_f(acc[rt][ct][0] + bb.x);
                float v1 = tanh_f(acc[rt][ct][1] + bb.y);
                float v2 = tanh_f(acc[rt][ct][2] + bb.z);
                float v3 = tanh_f(acc[rt][ct][3] + bb.w);
                #pragma unroll
                for (int m = 1; m <= 4; m <<= 1) {
                    v0 += __shfl_xor(v0, m); v1 += __shfl_xor(v1, m);
                    v2 += __shfl_xor(v2, m); v3 += __shfl_xor(v3, m);
                }
                if ((lm & 7) == 0) {
                    v0 *= 0.125f; v1 *= 0.125f; v2 *= 0.125f; v3 *= 0.125f;
                    unsigned h01 = cvtpk(v0, v1), h23 = cvtpk(v2, v3);
                    size_t g = (size_t)bidx * 8 + wr * 4 + rt * 2 + (lm >> 3);
                    *reinterpret_cast<uint2*>(mh + g * HID + j00 + ct * 16) = make_uint2(h01, h23);
                    if (use_ml) {
                        float f0 = __uint_as_float(h01 << 16), f1 = __uint_as_float(h01 & 0xffff0000u);
                        float f2 = __uint_as_float(h23 << 16), f3 = __uint_as_float(h23 & 0xffff0000u);
                        unsigned l01 = cvtpk(v0 - f0, v1 - f1), l23 = cvtpk(v2 - f2, v3 - f3);
                        *reinterpret_cast<uint2*>(mlp + g * HID + j00 + ct * 16) = make_uint2(l01, l23);
                    }
                }
            }
        }
    }
}

// ================= kernel B: full pipeline =================
__global__ __launch_bounds__(NTHREADS, 4)
void qk_main(const float* __restrict__ self_obs, const float* __restrict__ obs,
             const float* __restrict__ eb1, const float* __restrict__ eb2,
             const float* __restrict__ vb1, const float* __restrict__ vb2,
             const float* __restrict__ ab1, const float* __restrict__ ab2,
             const float* __restrict__ aW3,
             const short* __restrict__ ws, float* __restrict__ out, int use_ml)
{
    __shared__ __align__(16) short X0h[RB * X0S], X0l[RB * X0S];   // 8 KB
    __shared__ __align__(16) short XPh[RB * HID], XPl[RB * HID];   // 32 KB
    __shared__ __align__(16) short Eh[RB * HID],  El[RB * HID];    // 32 KB
    __shared__ float spart[8][RB];                                  // 2 KB
    __shared__ float attnb[RB];

    const int tid = threadIdx.x, lane = tid & 63, w = tid >> 6;
    const int wr = w >> 2, wc = w & 3;
    const int lm = lane & 15, q = lane >> 4, q8 = q << 3;
    const int swz = (lm & 7) << 3;
    const int swz_lo = swz & 0x18, swz_hi = swz & 0x20;
    const int rowb = wr * 32 + lm;
    const int xboff = rowb * HID + (q8 ^ swz_lo);
    const int xbE = xboff + swz_hi, xbO = xboff - swz_hi;
    const int j00 = wc * 32 + (q << 2);
    const int st0 = rowb * HID + ((wc * 32 + (q << 2)) ^ swz);
    const int st1 = rowb * HID + ((wc * 32 + 16 + (q << 2)) ^ swz);
    const int x0off = rowb * X0S + q8;
    const int c0 = wc * 32 + lm;
    const int off32 = c0 * 32 + q8, off128 = c0 * 128 + q8, off256 = c0 * 256 + q8;
    const int bidx = remap_bid(blockIdx.x);
    const int r0 = bidx * RB;

    WF1 f1 = loadW1<32>(ws + E1H + off32, ws + E1L + off32);
    build_x0(X0h, X0l, self_obs, obs, r0, tid);
    __syncthreads();                                               // B1

    f32x4 acc[2][2];

    // ---- L1: tanh(X0 @ eW1 + eb1) -> XP
    zacc(acc);
    mmT1(acc, f1, X0h + x0off, X0l + x0off);
    WF4 f2 = loadW4<128>(ws + E2H + off128, ws + E2L + off128);
    epi_tanh_store(acc, eb1, XPh, XPl, j00, st0, st1);
    __syncthreads();                                               // B2

    // ---- L2: tanh(XP @ eW2 + eb2) -> E
    zacc(acc);
    mmT4(acc, f2, XPh + xbE, XPh + xbO, XPl + xbE, XPl + xbO);
    WF4 f5e = loadW4<256>(ws + A1H + off256, ws + A1L + off256);
    epi_tanh_store(acc, eb2, Eh, El, j00, st0, st1);
    __syncthreads();                                               // B3

    // ---- L5a: emb half of tanh([emb|mean] @ aW1 + ab1); mean rows -> regs (async-ish)
    bf16x8 mrh[2], mrl[2];
    {
        const short* gmh = ws + MEANH + (size_t)(r0 & (BATCH - 1)) * HID;
        #pragma unroll
        for (int s = 0; s < 2; ++s) {
            int ch = tid + s * 512, r = ch >> 4, ce = (ch & 15) * 8;
            mrh[s] = *(const bf16x8*)(gmh + r * HID + ce);
            if (use_ml) mrl[s] = *(const bf16x8*)(gmh + (MEANL - MEANH) + r * HID + ce);
        }
    }
    zacc(acc);
    mmT4(acc, f5e, Eh + xbE, Eh + xbO, El + xbE, El + xbO);
    // stage mean into dead XP region (swizzled); zero lo if not available
    {
        const bf16x8 z8 = {0, 0, 0, 0, 0, 0, 0, 0};
        #pragma unroll
        for (int s = 0; s < 2; ++s) {
            int ch = tid + s * 512, r = ch >> 4, ce = (ch & 15) * 8;
            int e = r * HID + (ce ^ ((r & 7) << 3));
            *(bf16x8*)(XPh + e) = mrh[s];
            *(bf16x8*)(XPl + e) = use_ml ? mrl[s] : z8;
        }
    }
    WF4 f5m = loadW4<256>(ws + A1H + off256 + 128, ws + A1L + off256 + 128);
    __syncthreads();                                               // B4 (mean staged)

    // ---- L5b: mean half (accumulates into same acc)
    mmT4(acc, f5m, XPh + xbE, XPh + xbO, XPl + xbE, XPl + xbO);
    WF4 f6 = loadW4<128>(ws + A2H + off128, ws + A2L + off128);
    __syncthreads();                                               // B5 (mean reads done)
    epi_tanh_store(acc, ab1, XPh, XPl, j00, st0, st1);
    __syncthreads();                                               // B6

    // ---- L6: h2 = tanh(XP @ aW2 + ab2); score partials (ab3 cancels in softmax)
    zacc(acc);
    mmT4(acc, f6, XPh + xbE, XPh + xbO, XPl + xbE, XPl + xbO);
    WF4 f3 = loadW4<128>(ws + V1H + off128, ws + V1L + off128);
    {
        float part[2] = {0.f, 0.f};
        #pragma unroll
        for (int ct = 0; ct < 2; ++ct) {
            float4 bb = ld4(&ab2[j00 + ct * 16]);
            float4 w3 = ld4(&aW3[j00 + ct * 16]);
            #pragma unroll
            for (int rt = 0; rt < 2; ++rt) {
                part[rt] += tanh_f(acc[rt][ct][0] + bb.x) * w3.x
                          + tanh_f(acc[rt][ct][1] + bb.y) * w3.y
                          + tanh_f(acc[rt][ct][2] + bb.z) * w3.z
                          + tanh_f(acc[rt][ct][3] + bb.w) * w3.w;
            }
        }
        #pragma unroll
        for (int rt = 0; rt < 2; ++rt) {
            part[rt] += __shfl_xor(part[rt], 16);
            part[rt] += __shfl_xor(part[rt], 32);
            if (q == 0) spart[w][wr * 32 + rt * 16 + lm] = part[rt];
        }
    }
    __syncthreads();                                               // B7

    // ---- softmax (wave 0, lanes 0-7) in parallel with L3 mmT
    if (w == 0 && lane < 8) {
        const int g = lane;
        const int wb = (g >> 2) * 4;
        float sc[8];
        #pragma unroll
        for (int k = 0; k < 8; ++k)
            sc[k] = spart[wb + 0][g * 8 + k] + spart[wb + 1][g * 8 + k]
                  + spart[wb + 2][g * 8 + k] + spart[wb + 3][g * 8 + k];
        float mx = -1e30f;
        #pragma unroll
        for (int k = 0; k < 8; ++k) mx = fmaxf(mx, sc[k]);
        float es[8], ssum = 0.f;
        #pragma unroll
        for (int k = 0; k < 8; ++k) { es[k] = __expf(sc[k] - mx); ssum += es[k]; }
        float inv = __builtin_amdgcn_rcpf(ssum);
        #pragma unroll
        for (int k = 0; k < 8; ++k) attnb[g * 8 + k] = es[k] * inv;
    }

    // ---- L3: tanh(E @ vW1 + vb1) -> XP
    zacc(acc);
    mmT4(acc, f3, Eh + xbE, Eh + xbO, El + xbE, El + xbO);
    WF4 f4 = loadW4<128>(ws + V2H + off128, ws + V2L + off128);
    epi_tanh_store(acc, vb1, XPh, XPl, j00, st0, st1);
    __syncthreads();                                               // B8

    // ---- L4: vals = tanh(XP @ vW2 + vb2); out = sum_group attn * vals
    zacc(acc);
    mmT4(acc, f4, XPh + xbE, XPh + xbO, XPl + xbE, XPl + xbO);
    #pragma unroll
    for (int ct = 0; ct < 2; ++ct) {
        float4 bb = ld4(&vb2[j00 + ct * 16]);
        #pragma unroll
        for (int rt = 0; rt < 2; ++rt) {
            float a = attnb[wr * 32 + rt * 16 + lm];
            float s0 = a * tanh_f(acc[rt][ct][0] + bb.x);
            float s1 = a * tanh_f(acc[rt][ct][1] + bb.y);
            float s2 = a * tanh_f(acc[rt][ct][2] + bb.z);
            float s3 = a * tanh_f(acc[rt][ct][3] + bb.w);
            #pragma unroll
            for (int m = 1; m <= 4; m <<= 1) {
                s0 += __shfl_xor(s0, m); s1 += __shfl_xor(s1, m);
                s2 += __shfl_xor(s2, m); s3 += __shfl_xor(s3, m);
            }
            if ((lm & 7) == 0) {
                size_t b = (size_t)bidx * 8 + wr * 4 + rt * 2 + (lm >> 3);
                *reinterpret_cast<float4*>(&out[b * HID + j00 + ct * 16]) = make_float4(s0, s1, s2, s3);
            }
        }
    }
}

extern "C" void kernel_launch(void* const* d_in, const int* in_sizes, int n_in,
                              void* d_out, int out_size, void* d_ws, size_t ws_size,
                              hipStream_t stream) {
    const float* self_obs = (const float*)d_in[0];
    const float* obs      = (const float*)d_in[1];
    const float* eW1 = (const float*)d_in[2];  const float* eb1 = (const float*)d_in[3];
    const float* eW2 = (const float*)d_in[4];  const float* eb2 = (const float*)d_in[5];
    const float* vW1 = (const float*)d_in[6];  const float* vb1 = (const float*)d_in[7];
    const float* vW2 = (const float*)d_in[8];  const float* vb2 = (const float*)d_in[9];
    const float* aW1 = (const float*)d_in[10]; const float* ab1 = (const float*)d_in[11];
    const float* aW2 = (const float*)d_in[12]; const float* ab2 = (const float*)d_in[13];
    const float* aW3 = (const float*)d_in[14];
    float* out = (float*)d_out;
    short* ws = (short*)d_ws;

    int use_ml = (ws_size >= (size_t)WS_ELEMS_FULL * sizeof(short)) ? 1 : 0;

    prep_w<<<400, 256, 0, stream>>>(eW1, eW2, vW1, vW2, aW1, aW2, ws);

    dim3 grid(BATCH * 8 / RB);   // 8192
    qk_mean<<<grid, NTHREADS, 0, stream>>>(self_obs, obs, eb1, eb2, ws, use_ml);
    qk_main<<<grid, NTHREADS, 0, stream>>>(self_obs, obs, eb1, eb2, vb1, vb2,
                                           ab1, ab2, aW3, ws, out, use_ml);
}